// Round 2
// baseline (57.229 us; speedup 1.0000x reference)
//
#include <hip/hip_runtime.h>
#include <math.h>

#define BLOCK 128
#define U 8

namespace {
constexpr int NPIX = 4096;                    // 64x64
constexpr int NBATCH = 8;
constexpr int NOFF = 127 * 127;               // 16129
constexpr int D2MAX = 2 * 63 * 63;            // 7938
constexpr int CHUNKS = NPIX / BLOCK;          // 32 blocks/batch, 2 rows each
constexpr int LW = 192;                       // 64-col zero halo each side
constexpr int LDSN = 64 * LW;                 // 12288 floats = 48 KB
constexpr int NMAIN = ((NOFF + 2 * U - 1) / (2 * U)) * (2 * U);  // 16144
constexpr int NOFFP = NMAIN + 2 * U;          // covers deepest speculative TLOAD
constexpr int NSTAGE = 1024;                  // staged table prefix (8 KB LDS)
constexpr int LIMIT1 = NSTAGE - 2 * U;        // 1008: loop-1 bound (deepest
                                              // speculative TLOAD = LIMIT1+2U-1
                                              // = 1023 = NSTAGE-1)

// AoS so one 16B LDS read yields two (rel, d2) entries.
struct Pair { int rel; float d2; };
struct alignas(16) Tab { Pair p[NOFFP]; };

// Compile-time counting sort of all (dy,dx) by d2 = dy^2+dx^2. Intra-shell
// order is irrelevant (equal d2 multiplier -> truncated shell mass is
// order-free). rel = dy*LW+dx pre-bakes the LDS address delta. Pad entries
// have rel forced out-of-range -> they read the w[LDSN-1] halo zero.
constexpr Tab make_table() {
  Tab t{};
  int pos[D2MAX + 1] = {};
  for (int dy = -63; dy <= 63; ++dy)
    for (int dx = -63; dx <= 63; ++dx) pos[dy * dy + dx * dx] += 1;
  int acc = 0;
  for (int d = 0; d <= D2MAX; ++d) { int c = pos[d]; pos[d] = acc; acc += c; }
  for (int dy = -63; dy <= 63; ++dy)
    for (int dx = -63; dx <= 63; ++dx) {
      const int d2 = dy * dy + dx * dx;
      const int p = pos[d2]++;
      t.p[p].d2 = (float)d2;
      t.p[p].rel = dy * LW + dx;
    }
  for (int q = NOFF; q < NOFFP; ++q) { t.p[q].d2 = 0.f; t.p[q].rel = 4 * LDSN; }
  return t;
}
}  // namespace

__device__ constexpr Tab g_tab = make_table();

__global__ __launch_bounds__(BLOCK) void dtm_kernel(const float* __restrict__ x,
                                                    float* __restrict__ out) {
  __shared__ __align__(16) float w[LDSN];
  __shared__ __align__(16) int2 tl[NSTAGE];   // staged (rel, d2) prefix
  __shared__ float wavesum[2];

  const int b = blockIdx.x / CHUNKS;
  const int chunk = blockIdx.x % CHUNKS;
  const int tid = threadIdx.x;

  // --- T14 async-STAGE split: issue ALL global loads first (into regs),
  //     do the halo zeroing while they're in flight, then write them to
  //     LDS. At 2 waves/CU there is no TLP to hide the ~900-cy cold HBM
  //     latency, so it must hide under the halo ILP instead.
  const float4* __restrict__ xb4 = (const float4*)(x + b * NPIX);
  float4 vimg[NPIX / 4 / BLOCK];               // 8 float4 = 32 VGPRs
#pragma unroll
  for (int k = 0; k < NPIX / 4 / BLOCK; ++k) vimg[k] = xb4[k * BLOCK + tid];

  const float4* __restrict__ t4 = (const float4*)g_tab.p;
  float4 vtab[(NSTAGE * 8) / 16 / BLOCK];      // 4 float4 = 16 VGPRs
#pragma unroll
  for (int k = 0; k < (NSTAGE * 8) / 16 / BLOCK; ++k)
    vtab[k] = t4[k * BLOCK + tid];

  // --- zero only the halos (cols [0,64) and [128,192) of each row);
  //     disjoint from the staged center, so no barrier needed in between.
  float4* w4 = (float4*)w;
#pragma unroll
  for (int k = 0; k < 16; ++k) {
    const int h = k * BLOCK + tid;  // 0..2047 halo-float4 id
    const int row = h >> 5;         // 32 halo float4s per row
    const int c = h & 31;
    w4[row * 48 + (c < 16 ? c : c + 16)] = float4{0.f, 0.f, 0.f, 0.f};
  }

  // --- drain loads into LDS center (coalesced float4) + total mass
  float local = 0.f;
#pragma unroll
  for (int k = 0; k < NPIX / 4 / BLOCK; ++k) {  // 8
    const int p4 = k * BLOCK + tid;
    const float4 v = vimg[k];
    const int row = p4 >> 4;       // 16 float4 per image row
    const int col = (p4 & 15) << 2;
    *(float4*)&w[row * LW + 64 + col] = v;
    local += (v.x + v.y) + (v.z + v.w);
  }

  // --- table prefix into LDS (pure bit-copy). All hot-loop memory ops
  //     become in-order ds_reads -> partial lgkmcnt waits instead of the
  //     SMEM-forced lgkmcnt(0) full drains.
  {
    float4* l4 = (float4*)tl;
#pragma unroll
    for (int k = 0; k < (NSTAGE * 8) / 16 / BLOCK; ++k)  // 4
      l4[k * BLOCK + tid] = vtab[k];
  }

#pragma unroll
  for (int off = 32; off; off >>= 1) local += __shfl_xor(local, off);
  if ((tid & 63) == 0) wavesum[tid >> 6] = local;
  __syncthreads();  // orders halo zeros + center stage + table stage + wavesum
  const float T = 0.01f * (wavesum[0] + wavesum[1]);  // M0 * total_mass

  // --- walk offsets in d2 order. Invalid addresses (row out of range, pad
  //     entries) all collapse via unsigned min onto w[LDSN-1], a halo zero —
  //     value-exact, no compare/select needed.
  const int pix = chunk * BLOCK + tid;
  const int base = (pix >> 6) * LW + (pix & 63) + 64;

  float cum = 0.f, wds = 0.f;
  int relA[U], relB[U];
  float d2A[U], d2B[U], wvA[U], wvB[U];

// table read from LDS prefix: ds_read_b128 = 2 entries, uniform addr broadcast
#define TLOADL(BASE, REL, D2)                             \
  _Pragma("unroll") for (int u2 = 0; u2 < U / 2; ++u2) {  \
    const int4 q = *(const int4*)&tl[(BASE) + 2 * u2];    \
    REL[2 * u2] = q.x;                                    \
    D2[2 * u2] = __int_as_float(q.y);                     \
    REL[2 * u2 + 1] = q.z;                                \
    D2[2 * u2 + 1] = __int_as_float(q.w);                 \
  }

// table read from global (rare fallback past the staged prefix)
#define TLOADG(BASE, REL, D2)                      \
  _Pragma("unroll") for (int u = 0; u < U; ++u) {  \
    REL[u] = g_tab.p[(BASE) + u].rel;              \
    D2[u] = g_tab.p[(BASE) + u].d2;                \
  }

#define WLOAD(REL, WV)                                                     \
  _Pragma("unroll") for (int u = 0; u < U; ++u) {                          \
    WV[u] = w[min((unsigned)(base + REL[u]), (unsigned)(LDSN - 1))];       \
  }

#define ACC(WV, D2)                                \
  _Pragma("unroll") for (int u = 0; u < U; ++u) {  \
    float rem = T - cum;                           \
    rem = rem > 0.f ? rem : 0.f;                   \
    const float eff = WV[u] < rem ? WV[u] : rem;   \
    wds = fmaf(eff, D2[u], wds);                   \
    cum += WV[u];                                  \
  }

  // depth-2 software pipeline, A/B ping-pong, 2 groups of U per body.
  // Loop 1: all-LDS (table prefix). Loop 2: global-table fallback, entered
  // only if some lane hasn't reached T after 1008 offsets (not on this
  // input distribution; worst case = corner pixel ~250 offsets).
  TLOADL(0, relA, d2A);
  WLOAD(relA, wvA);
  TLOADL(U, relB, d2B);

  bool done = false;
  for (int i = 0; i < LIMIT1; i += 2 * U) {
    WLOAD(relB, wvB);                // group g+1 ds_reads (independent)
    ACC(wvA, d2A);                   // group g (covers load latency)
    if (__all(cum >= T)) { done = true; break; }
    TLOADL(i + 2 * U, relA, d2A);    // group g+2 table (LDS, in-order)
    ACC(wvB, d2B);                   // group g+1
    if (__all(cum >= T)) { done = true; break; }
    WLOAD(relA, wvA);                // group g+2 ds_reads
    TLOADL(i + 3 * U, relB, d2B);    // group g+3 table
  }

  if (!done) {
    // Pipeline hand-off is seamless: at loop-1 natural exit, A = group
    // LIMIT1 (table+weights loaded), B = group LIMIT1+U (table loaded from
    // entries 1016..1023). First global TLOAD index = LIMIT1+2U = NSTAGE.
    for (int i = LIMIT1; i < NMAIN; i += 2 * U) {
      WLOAD(relB, wvB);
      ACC(wvA, d2A);
      if (__all(cum >= T)) break;
      TLOADG(i + 2 * U, relA, d2A);
      ACC(wvB, d2B);
      if (__all(cum >= T)) break;
      WLOAD(relA, wvA);
      TLOADG(i + 3 * U, relB, d2B);
    }
  }
#undef TLOADL
#undef TLOADG
#undef WLOAD
#undef ACC

  const float res = (T > 0.f) ? sqrtf(wds / T) : 0.f;
  out[b * NPIX + pix] = res;
}

extern "C" void kernel_launch(void* const* d_in, const int* in_sizes, int n_in,
                              void* d_out, int out_size, void* d_ws, size_t ws_size,
                              hipStream_t stream) {
  (void)in_sizes; (void)n_in; (void)out_size; (void)d_ws; (void)ws_size;
  const float* x = (const float*)d_in[0];
  float* out = (float*)d_out;
  dtm_kernel<<<dim3(NBATCH * CHUNKS), dim3(BLOCK), 0, stream>>>(x, out);
}